// Round 1
// baseline (4092.315 us; speedup 1.0000x reference)
//
#include <hip/hip_runtime.h>
#include <math.h>

// ---------------------------------------------------------------------------
// GIN link scorer:
//   h1 = relu(relu((x+agg(x))@w1a+b1a)@w2a+b2a)            [N,64]
//   h2 = relu((h1+agg(h1))@w1b+b1b)@w2b+b2b                [N,32]
//   out[c] = sigmoid(h2[a]·ws[0:32] + h2[b]·ws[32:64] + bs)
// Trick: fold ws into per-node scalars z1,z2 so the pair kernel gathers
// 2 floats instead of 64.
// ---------------------------------------------------------------------------

// K1: agg1[dst] += x[src]  (7-dim)
__global__ void scatter_x_kernel(const float* __restrict__ x,
                                 const int* __restrict__ src,
                                 const int* __restrict__ dst,
                                 float* __restrict__ agg1, int E) {
    int e = blockIdx.x * blockDim.x + threadIdx.x;
    if (e >= E) return;
    int s = src[e], d = dst[e];
    const float* xs = x + (long)s * 7;
    float* ad = agg1 + (long)d * 7;
#pragma unroll
    for (int j = 0; j < 7; ++j) atomicAdd(&ad[j], xs[j]);
}

// K2: h1 = relu(relu((x+agg1)@w1a+b1a)@w2a+b2a), one thread per node
__global__ __launch_bounds__(256) void mlpA_kernel(
    const float* __restrict__ x, const float* __restrict__ agg1,
    const float* __restrict__ w1, const float* __restrict__ b1,
    const float* __restrict__ w2, const float* __restrict__ b2,
    float* __restrict__ h1, int N) {
    __shared__ float sw1[7 * 64];
    __shared__ float sb1[64];
    __shared__ float sw2[64 * 64];
    __shared__ float sb2[64];
    for (int i = threadIdx.x; i < 7 * 64; i += blockDim.x) sw1[i] = w1[i];
    for (int i = threadIdx.x; i < 64; i += blockDim.x) { sb1[i] = b1[i]; sb2[i] = b2[i]; }
    for (int i = threadIdx.x; i < 64 * 64; i += blockDim.x) sw2[i] = w2[i];
    __syncthreads();

    int n = blockIdx.x * blockDim.x + threadIdx.x;
    if (n >= N) return;

    float xv[7];
#pragma unroll
    for (int j = 0; j < 7; ++j) xv[j] = x[(long)n * 7 + j] + agg1[(long)n * 7 + j];

    float t[64];
#pragma unroll
    for (int k = 0; k < 64; ++k) {
        float s = sb1[k];
#pragma unroll
        for (int j = 0; j < 7; ++j) s = fmaf(xv[j], sw1[j * 64 + k], s);
        t[k] = fmaxf(s, 0.0f);
    }

    float* hrow = h1 + (long)n * 64;
    for (int k2 = 0; k2 < 64; ++k2) {
        float s = sb2[k2];
#pragma unroll 8
        for (int k = 0; k < 64; ++k) s = fmaf(t[k], sw2[k * 64 + k2], s);
        hrow[k2] = fmaxf(s, 0.0f);
    }
}

// K3: agg2[dst] += h1[src]  (64-dim), one thread per (edge,feature)
__global__ void scatter_h1_kernel(const float* __restrict__ h1,
                                  const int* __restrict__ src,
                                  const int* __restrict__ dst,
                                  float* __restrict__ agg2, long E) {
    long gid = (long)blockIdx.x * blockDim.x + threadIdx.x;
    long e = gid >> 6;
    int f = (int)(gid & 63);
    if (e >= E) return;
    int s = src[e], d = dst[e];
    atomicAdd(&agg2[(long)d * 64 + f], h1[(long)s * 64 + f]);
}

// K4: per node -> z1 = h2·ws[0:32], z2 = h2·ws[32:64]
__global__ __launch_bounds__(256) void mlpB_kernel(
    const float* __restrict__ h1, const float* __restrict__ agg2,
    const float* __restrict__ w1, const float* __restrict__ b1,
    const float* __restrict__ w2, const float* __restrict__ b2,
    const float* __restrict__ wsv,
    float* __restrict__ z1, float* __restrict__ z2, int N) {
    __shared__ float sw1[64 * 32];
    __shared__ float sb1[32];
    __shared__ float sw2[32 * 32];
    __shared__ float sb2[32];
    __shared__ float sws[64];
    for (int i = threadIdx.x; i < 64 * 32; i += blockDim.x) sw1[i] = w1[i];
    for (int i = threadIdx.x; i < 32 * 32; i += blockDim.x) sw2[i] = w2[i];
    for (int i = threadIdx.x; i < 32; i += blockDim.x) { sb1[i] = b1[i]; sb2[i] = b2[i]; }
    for (int i = threadIdx.x; i < 64; i += blockDim.x) sws[i] = wsv[i];
    __syncthreads();

    int n = blockIdx.x * blockDim.x + threadIdx.x;
    if (n >= N) return;

    float hp[64];
#pragma unroll 8
    for (int k = 0; k < 64; ++k) hp[k] = h1[(long)n * 64 + k] + agg2[(long)n * 64 + k];

    float u[32];
    for (int m = 0; m < 32; ++m) {
        float s = sb1[m];
#pragma unroll 8
        for (int k = 0; k < 64; ++k) s = fmaf(hp[k], sw1[k * 32 + m], s);
        u[m] = fmaxf(s, 0.0f);
    }

    float a = 0.0f, b = 0.0f;
    for (int m2 = 0; m2 < 32; ++m2) {
        float s = sb2[m2];
#pragma unroll 8
        for (int m = 0; m < 32; ++m) s = fmaf(u[m], sw2[m * 32 + m2], s);
        a = fmaf(s, sws[m2], a);
        b = fmaf(s, sws[32 + m2], b);
    }
    z1[n] = a;
    z2[n] = b;
}

// K5: out[c] = sigmoid(z1[cand0] + z2[cand1] + bs)
__global__ void score_kernel(const int* __restrict__ cand,
                             const float* __restrict__ z1,
                             const float* __restrict__ z2,
                             const float* __restrict__ bs,
                             float* __restrict__ out, int C) {
    int c = blockIdx.x * blockDim.x + threadIdx.x;
    if (c >= C) return;
    int a = cand[2 * c], b = cand[2 * c + 1];
    float s = z1[a] + z2[b] + bs[0];
    out[c] = 1.0f / (1.0f + expf(-s));
}

extern "C" void kernel_launch(void* const* d_in, const int* in_sizes, int n_in,
                              void* d_out, int out_size, void* d_ws, size_t ws_size,
                              hipStream_t stream) {
    const float* x   = (const float*)d_in[0];
    const int* edge  = (const int*)d_in[1];
    const int* cand  = (const int*)d_in[2];
    const float* w1a = (const float*)d_in[3];
    const float* b1a = (const float*)d_in[4];
    const float* w2a = (const float*)d_in[5];
    const float* b2a = (const float*)d_in[6];
    const float* w1b = (const float*)d_in[7];
    const float* b1b = (const float*)d_in[8];
    const float* w2b = (const float*)d_in[9];
    const float* b2b = (const float*)d_in[10];
    const float* wsv = (const float*)d_in[11];
    const float* bs  = (const float*)d_in[12];

    const int  N = in_sizes[0] / 7;
    const long E = in_sizes[1] / 2;
    const int  C = in_sizes[2] / 2;
    const int* src = edge;
    const int* dst = edge + E;

    float* wsf = (float*)d_ws;
    size_t off = 0;
    float* agg1 = wsf + off; off += (size_t)N * 7;   // 0.7M floats
    float* h1   = wsf + off; off += (size_t)N * 64;  // 6.4M floats
    float* agg2 = wsf + off; off += (size_t)N * 64;  // 6.4M floats
    float* z1   = wsf + off; off += (size_t)N;
    float* z2   = wsf + off; off += (size_t)N;
    (void)ws_size;

    hipMemsetAsync(agg1, 0, (size_t)N * 7 * sizeof(float), stream);
    hipMemsetAsync(agg2, 0, (size_t)N * 64 * sizeof(float), stream);

    {
        int blocks = (int)((E + 255) / 256);
        scatter_x_kernel<<<blocks, 256, 0, stream>>>(x, src, dst, agg1, (int)E);
    }
    {
        int blocks = (N + 255) / 256;
        mlpA_kernel<<<blocks, 256, 0, stream>>>(x, agg1, w1a, b1a, w2a, b2a, h1, N);
    }
    {
        long total = E * 64;
        int blocks = (int)((total + 255) / 256);
        scatter_h1_kernel<<<blocks, 256, 0, stream>>>(h1, src, dst, agg2, E);
    }
    {
        int blocks = (N + 255) / 256;
        mlpB_kernel<<<blocks, 256, 0, stream>>>(h1, agg2, w1b, b1b, w2b, b2b, wsv, z1, z2, N);
    }
    {
        int blocks = (C + 255) / 256;
        score_kernel<<<blocks, 256, 0, stream>>>(cand, z1, z2, bs, d_out ? (float*)d_out : nullptr, C);
    }
}

// Round 2
// 2238.417 us; speedup vs baseline: 1.8282x; 1.8282x over previous
//
#include <hip/hip_runtime.h>
#include <math.h>

// ---------------------------------------------------------------------------
// GIN link scorer:
//   h1 = relu(relu((x+agg(x))@w1a+b1a)@w2a+b2a)            [N,64]
//   h2 = relu((h1+agg(h1))@w1b+b1b)@w2b+b2b                [N,32]
//   out[c] = sigmoid(h2[a]·ws[0:32] + h2[b]·ws[32:64] + bs)
// Tricks:
//  - fold ws into per-node scalars z1,z2 so the pair kernel gathers 2 floats.
//  - scatter kernels use lane-per-(edge,feature) mapping so atomics within a
//    wave hit contiguous addresses (coalesced write sectors). agg1 padded to
//    stride 8 for 32B alignment.
// ---------------------------------------------------------------------------

// K1: agg1[dst*8 + f] += x[src*7 + f], 8 lanes per edge (f==7 idle)
__global__ void scatter_x_kernel(const float* __restrict__ x,
                                 const int* __restrict__ src,
                                 const int* __restrict__ dst,
                                 float* __restrict__ agg1, long E) {
    long gid = (long)blockIdx.x * blockDim.x + threadIdx.x;
    long e = gid >> 3;
    int f = (int)(gid & 7);
    if (e >= E) return;
    int s = src[e], d = dst[e];
    if (f < 7) {
        atomicAdd(&agg1[(long)d * 8 + f], x[(long)s * 7 + f]);
    }
}

// K2: h1 = relu(relu((x+agg1)@w1a+b1a)@w2a+b2a), one thread per node
__global__ __launch_bounds__(256) void mlpA_kernel(
    const float* __restrict__ x, const float* __restrict__ agg1,
    const float* __restrict__ w1, const float* __restrict__ b1,
    const float* __restrict__ w2, const float* __restrict__ b2,
    float* __restrict__ h1, int N) {
    __shared__ float sw1[7 * 64];
    __shared__ float sb1[64];
    __shared__ float sw2[64 * 64];
    __shared__ float sb2[64];
    for (int i = threadIdx.x; i < 7 * 64; i += blockDim.x) sw1[i] = w1[i];
    for (int i = threadIdx.x; i < 64; i += blockDim.x) { sb1[i] = b1[i]; sb2[i] = b2[i]; }
    for (int i = threadIdx.x; i < 64 * 64; i += blockDim.x) sw2[i] = w2[i];
    __syncthreads();

    int n = blockIdx.x * blockDim.x + threadIdx.x;
    if (n >= N) return;

    float xv[7];
#pragma unroll
    for (int j = 0; j < 7; ++j) xv[j] = x[(long)n * 7 + j] + agg1[(long)n * 8 + j];

    float t[64];
#pragma unroll
    for (int k = 0; k < 64; ++k) {
        float s = sb1[k];
#pragma unroll
        for (int j = 0; j < 7; ++j) s = fmaf(xv[j], sw1[j * 64 + k], s);
        t[k] = fmaxf(s, 0.0f);
    }

    float* hrow = h1 + (long)n * 64;
    for (int k2 = 0; k2 < 64; ++k2) {
        float s = sb2[k2];
#pragma unroll 8
        for (int k = 0; k < 64; ++k) s = fmaf(t[k], sw2[k * 64 + k2], s);
        hrow[k2] = fmaxf(s, 0.0f);
    }
}

// K3: agg2[dst] += h1[src]  (64-dim), one thread per (edge,feature)
__global__ void scatter_h1_kernel(const float* __restrict__ h1,
                                  const int* __restrict__ src,
                                  const int* __restrict__ dst,
                                  float* __restrict__ agg2, long E) {
    long gid = (long)blockIdx.x * blockDim.x + threadIdx.x;
    long e = gid >> 6;
    int f = (int)(gid & 63);
    if (e >= E) return;
    int s = src[e], d = dst[e];
    atomicAdd(&agg2[(long)d * 64 + f], h1[(long)s * 64 + f]);
}

// K4: per node -> z1 = h2·ws[0:32], z2 = h2·ws[32:64]
__global__ __launch_bounds__(256) void mlpB_kernel(
    const float* __restrict__ h1, const float* __restrict__ agg2,
    const float* __restrict__ w1, const float* __restrict__ b1,
    const float* __restrict__ w2, const float* __restrict__ b2,
    const float* __restrict__ wsv,
    float* __restrict__ z1, float* __restrict__ z2, int N) {
    __shared__ float sw1[64 * 32];
    __shared__ float sb1[32];
    __shared__ float sw2[32 * 32];
    __shared__ float sb2[32];
    __shared__ float sws[64];
    for (int i = threadIdx.x; i < 64 * 32; i += blockDim.x) sw1[i] = w1[i];
    for (int i = threadIdx.x; i < 32 * 32; i += blockDim.x) sw2[i] = w2[i];
    for (int i = threadIdx.x; i < 32; i += blockDim.x) { sb1[i] = b1[i]; sb2[i] = b2[i]; }
    for (int i = threadIdx.x; i < 64; i += blockDim.x) sws[i] = wsv[i];
    __syncthreads();

    int n = blockIdx.x * blockDim.x + threadIdx.x;
    if (n >= N) return;

    float hp[64];
#pragma unroll 8
    for (int k = 0; k < 64; ++k) hp[k] = h1[(long)n * 64 + k] + agg2[(long)n * 64 + k];

    float u[32];
    for (int m = 0; m < 32; ++m) {
        float s = sb1[m];
#pragma unroll 8
        for (int k = 0; k < 64; ++k) s = fmaf(hp[k], sw1[k * 32 + m], s);
        u[m] = fmaxf(s, 0.0f);
    }

    float a = 0.0f, b = 0.0f;
    for (int m2 = 0; m2 < 32; ++m2) {
        float s = sb2[m2];
#pragma unroll 8
        for (int m = 0; m < 32; ++m) s = fmaf(u[m], sw2[m * 32 + m2], s);
        a = fmaf(s, sws[m2], a);
        b = fmaf(s, sws[32 + m2], b);
    }
    z1[n] = a;
    z2[n] = b;
}

// K5: out[c] = sigmoid(z1[cand0] + z2[cand1] + bs)
__global__ void score_kernel(const int* __restrict__ cand,
                             const float* __restrict__ z1,
                             const float* __restrict__ z2,
                             const float* __restrict__ bs,
                             float* __restrict__ out, int C) {
    int c = blockIdx.x * blockDim.x + threadIdx.x;
    if (c >= C) return;
    int a = cand[2 * c], b = cand[2 * c + 1];
    float s = z1[a] + z2[b] + bs[0];
    out[c] = 1.0f / (1.0f + expf(-s));
}

extern "C" void kernel_launch(void* const* d_in, const int* in_sizes, int n_in,
                              void* d_out, int out_size, void* d_ws, size_t ws_size,
                              hipStream_t stream) {
    const float* x   = (const float*)d_in[0];
    const int* edge  = (const int*)d_in[1];
    const int* cand  = (const int*)d_in[2];
    const float* w1a = (const float*)d_in[3];
    const float* b1a = (const float*)d_in[4];
    const float* w2a = (const float*)d_in[5];
    const float* b2a = (const float*)d_in[6];
    const float* w1b = (const float*)d_in[7];
    const float* b1b = (const float*)d_in[8];
    const float* w2b = (const float*)d_in[9];
    const float* b2b = (const float*)d_in[10];
    const float* wsv = (const float*)d_in[11];
    const float* bs  = (const float*)d_in[12];

    const int  N = in_sizes[0] / 7;
    const long E = in_sizes[1] / 2;
    const int  C = in_sizes[2] / 2;
    const int* src = edge;
    const int* dst = edge + E;

    float* wsf = (float*)d_ws;
    size_t off = 0;
    float* agg1 = wsf + off; off += (size_t)N * 8;   // padded stride 8
    float* h1   = wsf + off; off += (size_t)N * 64;
    float* agg2 = wsf + off; off += (size_t)N * 64;
    float* z1   = wsf + off; off += (size_t)N;
    float* z2   = wsf + off; off += (size_t)N;
    (void)ws_size;

    hipMemsetAsync(agg1, 0, (size_t)N * 8 * sizeof(float), stream);
    hipMemsetAsync(agg2, 0, (size_t)N * 64 * sizeof(float), stream);

    {
        long total = E * 8;
        int blocks = (int)((total + 255) / 256);
        scatter_x_kernel<<<blocks, 256, 0, stream>>>(x, src, dst, agg1, E);
    }
    {
        int blocks = (N + 255) / 256;
        mlpA_kernel<<<blocks, 256, 0, stream>>>(x, agg1, w1a, b1a, w2a, b2a, h1, N);
    }
    {
        long total = E * 64;
        int blocks = (int)((total + 255) / 256);
        scatter_h1_kernel<<<blocks, 256, 0, stream>>>(h1, src, dst, agg2, E);
    }
    {
        int blocks = (N + 255) / 256;
        mlpB_kernel<<<blocks, 256, 0, stream>>>(h1, agg2, w1b, b1b, w2b, b2b, wsv, z1, z2, N);
    }
    {
        int blocks = (C + 255) / 256;
        score_kernel<<<blocks, 256, 0, stream>>>(cand, z1, z2, bs, d_out ? (float*)d_out : nullptr, C);
    }
}

// Round 3
// 1650.073 us; speedup vs baseline: 2.4801x; 1.3566x over previous
//
#include <hip/hip_runtime.h>
#include <math.h>

// ---------------------------------------------------------------------------
// GIN link scorer, CSR-based (no feature atomics):
//   CSR build: histogram(dst) -> scan -> bucket scatter of src (per call)
//   xsum = x + sum_{edges} x[src]        (wave/node, 8 slots x 8 feats)
//   h1   = relu(relu(xsum@w1a+b1a)@w2a+b2a)
//   fused: hp = h1 + sum h1[src]; u=relu(hp@w1b+b1b); s=u@w2b+b2b;
//          z1=s.ws[:32], z2=s.ws[32:]   (wave/node, lane=feature)
//   out[c] = sigmoid(z1[a]+z2[b]+bs)
// ---------------------------------------------------------------------------

__global__ void hist_kernel(const int* __restrict__ dst, int* __restrict__ deg, long E) {
    long e = (long)blockIdx.x * blockDim.x + threadIdx.x;
    if (e >= E) return;
    atomicAdd(&deg[dst[e]], 1);
}

// single-block exclusive scan; deg_cursor updated in place to exclusive
// prefix (becomes the scatter cursor); row_start gets a copy.
__global__ __launch_bounds__(1024) void scan_kernel(int* __restrict__ deg_cursor,
                                                    int* __restrict__ row_start, int N) {
    __shared__ int wsums[16];
    __shared__ int s_carry;
    int tid = threadIdx.x, lane = tid & 63, wid = tid >> 6;
    if (tid == 0) s_carry = 0;
    __syncthreads();
    for (int base = 0; base < N; base += 1024) {
        int i = base + tid;
        int v = (i < N) ? deg_cursor[i] : 0;
        int s = v;
#pragma unroll
        for (int ofs = 1; ofs < 64; ofs <<= 1) {
            int t = __shfl_up(s, ofs);
            if (lane >= ofs) s += t;
        }
        if (lane == 63) wsums[wid] = s;
        __syncthreads();
        if (wid == 0) {
            int w = (lane < 16) ? wsums[lane] : 0;
#pragma unroll
            for (int ofs = 1; ofs < 16; ofs <<= 1) {
                int t = __shfl_up(w, ofs);
                if (lane >= ofs) w += t;
            }
            if (lane < 16) wsums[lane] = w;
        }
        __syncthreads();
        int waveoff = (wid > 0) ? wsums[wid - 1] : 0;
        int incl = s + waveoff + s_carry;
        int excl = incl - v;
        if (i < N) { row_start[i] = excl; deg_cursor[i] = excl; }
        __syncthreads();
        if (tid == 1023) s_carry = incl;
        __syncthreads();
    }
}

__global__ void scatter_csr_kernel(const int* __restrict__ src, const int* __restrict__ dst,
                                   int* __restrict__ cursor, int* __restrict__ csr_src, long E) {
    long e = (long)blockIdx.x * blockDim.x + threadIdx.x;
    if (e >= E) return;
    int d = dst[e];
    int pos = atomicAdd(&cursor[d], 1);
    csr_src[pos] = src[e];
}

// xsum[n*8+f] = x[n*7+f] + sum over edges; wave per node, lane = slot*8+f
__global__ __launch_bounds__(256) void agg1_kernel(const float* __restrict__ x,
                                                   const int* __restrict__ csr_src,
                                                   const int* __restrict__ row_start,
                                                   const int* __restrict__ row_end,
                                                   float* __restrict__ xsum, int N) {
    int wid = threadIdx.x >> 6, lane = threadIdx.x & 63;
    int n = blockIdx.x * 4 + wid;
    if (n >= N) return;
    int slot = lane >> 3, f = lane & 7;
    int start = row_start[n], end = row_end[n];
    float acc = 0.0f;
    for (int e = start + slot; e < end; e += 8) {
        int s = csr_src[e];
        if (f < 7) acc += x[(long)s * 7 + f];
    }
    acc += __shfl_xor(acc, 8);
    acc += __shfl_xor(acc, 16);
    acc += __shfl_xor(acc, 32);
    if (slot == 0 && f < 7) xsum[(long)n * 8 + f] = acc + x[(long)n * 7 + f];
}

// h1 = relu(relu(xsum@w1a+b1a)@w2a+b2a), one thread per node
__global__ __launch_bounds__(256) void mlpA_kernel(
    const float* __restrict__ xsum,
    const float* __restrict__ w1, const float* __restrict__ b1,
    const float* __restrict__ w2, const float* __restrict__ b2,
    float* __restrict__ h1, int N) {
    __shared__ float sw1[7 * 64];
    __shared__ float sb1[64];
    __shared__ float sw2[64 * 64];
    __shared__ float sb2[64];
    for (int i = threadIdx.x; i < 7 * 64; i += blockDim.x) sw1[i] = w1[i];
    for (int i = threadIdx.x; i < 64; i += blockDim.x) { sb1[i] = b1[i]; sb2[i] = b2[i]; }
    for (int i = threadIdx.x; i < 64 * 64; i += blockDim.x) sw2[i] = w2[i];
    __syncthreads();

    int n = blockIdx.x * blockDim.x + threadIdx.x;
    if (n >= N) return;

    float xv[7];
#pragma unroll
    for (int j = 0; j < 7; ++j) xv[j] = xsum[(long)n * 8 + j];

    float t[64];
#pragma unroll
    for (int k = 0; k < 64; ++k) {
        float s = sb1[k];
#pragma unroll
        for (int j = 0; j < 7; ++j) s = fmaf(xv[j], sw1[j * 64 + k], s);
        t[k] = fmaxf(s, 0.0f);
    }

    float* hrow = h1 + (long)n * 64;
    for (int k2 = 0; k2 < 64; ++k2) {
        float s = sb2[k2];
#pragma unroll 8
        for (int k = 0; k < 64; ++k) s = fmaf(t[k], sw2[k * 64 + k2], s);
        hrow[k2] = fmaxf(s, 0.0f);
    }
}

// fused layer-2 aggregate + MLP-B + ws fold. wave per node, lane = feature.
__global__ __launch_bounds__(256) void agg2_mlpB_kernel(
    const float* __restrict__ h1, const int* __restrict__ csr_src,
    const int* __restrict__ row_start, const int* __restrict__ row_end,
    const float* __restrict__ w1, const float* __restrict__ b1,
    const float* __restrict__ w2, const float* __restrict__ b2,
    const float* __restrict__ wsv,
    float* __restrict__ z1, float* __restrict__ z2, int N) {
    __shared__ float sw1[64 * 32];
    __shared__ float sw2[32 * 32];
    __shared__ float sb1[32], sb2[32];
    __shared__ float sws[64];
    __shared__ float shp[4][64];
    __shared__ float su[4][32];
    for (int i = threadIdx.x; i < 64 * 32; i += blockDim.x) sw1[i] = w1[i];
    for (int i = threadIdx.x; i < 32 * 32; i += blockDim.x) sw2[i] = w2[i];
    for (int i = threadIdx.x; i < 32; i += blockDim.x) { sb1[i] = b1[i]; sb2[i] = b2[i]; }
    for (int i = threadIdx.x; i < 64; i += blockDim.x) sws[i] = wsv[i];
    __syncthreads();

    int wid = threadIdx.x >> 6, lane = threadIdx.x & 63;
    int n = blockIdx.x * 4 + wid;
    bool valid = (n < N);
    int start = valid ? row_start[n] : 0;
    int end   = valid ? row_end[n]   : 0;

    float a0 = 0.0f, a1 = 0.0f, a2 = 0.0f, a3 = 0.0f;
    int e = start;
    for (; e + 3 < end; e += 4) {
        int s0 = csr_src[e], s1 = csr_src[e + 1], s2 = csr_src[e + 2], s3 = csr_src[e + 3];
        a0 += h1[(long)s0 * 64 + lane];
        a1 += h1[(long)s1 * 64 + lane];
        a2 += h1[(long)s2 * 64 + lane];
        a3 += h1[(long)s3 * 64 + lane];
    }
    for (; e < end; ++e) a0 += h1[(long)csr_src[e] * 64 + lane];
    float hp = (a0 + a1) + (a2 + a3);
    if (valid) hp += h1[(long)n * 64 + lane];

    shp[wid][lane] = hp;
    __syncthreads();

    float sval = 0.0f;
    if (lane < 32) {
        float s = sb1[lane];
#pragma unroll 8
        for (int k = 0; k < 64; ++k) s = fmaf(shp[wid][k], sw1[k * 32 + lane], s);
        su[wid][lane] = fmaxf(s, 0.0f);
    }
    __syncthreads();
    if (lane < 32) {
        float s = sb2[lane];
#pragma unroll 8
        for (int m = 0; m < 32; ++m) s = fmaf(su[wid][m], sw2[m * 32 + lane], s);
        sval = s;
    }
    float p = (lane < 32) ? sval * sws[lane] : 0.0f;
    float q = (lane < 32) ? sval * sws[32 + lane] : 0.0f;
#pragma unroll
    for (int m = 1; m < 32; m <<= 1) {
        p += __shfl_xor(p, m);
        q += __shfl_xor(q, m);
    }
    if (valid && lane == 0) { z1[n] = p; z2[n] = q; }
}

__global__ void score_kernel(const int* __restrict__ cand,
                             const float* __restrict__ z1,
                             const float* __restrict__ z2,
                             const float* __restrict__ bs,
                             float* __restrict__ out, int C) {
    int c = blockIdx.x * blockDim.x + threadIdx.x;
    if (c >= C) return;
    int a = cand[2 * c], b = cand[2 * c + 1];
    float s = z1[a] + z2[b] + bs[0];
    out[c] = 1.0f / (1.0f + expf(-s));
}

extern "C" void kernel_launch(void* const* d_in, const int* in_sizes, int n_in,
                              void* d_out, int out_size, void* d_ws, size_t ws_size,
                              hipStream_t stream) {
    const float* x   = (const float*)d_in[0];
    const int* edge  = (const int*)d_in[1];
    const int* cand  = (const int*)d_in[2];
    const float* w1a = (const float*)d_in[3];
    const float* b1a = (const float*)d_in[4];
    const float* w2a = (const float*)d_in[5];
    const float* b2a = (const float*)d_in[6];
    const float* w1b = (const float*)d_in[7];
    const float* b1b = (const float*)d_in[8];
    const float* w2b = (const float*)d_in[9];
    const float* b2b = (const float*)d_in[10];
    const float* wsv = (const float*)d_in[11];
    const float* bs  = (const float*)d_in[12];

    const int  N = in_sizes[0] / 7;
    const long E = in_sizes[1] / 2;
    const int  C = in_sizes[2] / 2;
    const int* src = edge;
    const int* dst = edge + E;

    // workspace layout (all 4B elems): deg/cursor N | row_start N | csr_src E |
    // xsum N*8 (z1/z2 alias after mlpA) | h1 N*64   => 74N + E elems = 55.2 MB
    int* deg_cursor = (int*)d_ws;                 // N: deg -> excl prefix -> seg end
    int* row_start  = deg_cursor + N;             // N
    int* csr_src    = row_start + N;              // E
    float* xsum     = (float*)(csr_src + E);      // N*8
    float* h1       = xsum + (size_t)N * 8;       // N*64
    float* z1       = xsum;                        // alias: xsum dead after mlpA
    float* z2       = xsum + N;
    (void)ws_size;

    hipMemsetAsync(deg_cursor, 0, (size_t)N * sizeof(int), stream);

    {
        int blocks = (int)((E + 255) / 256);
        hist_kernel<<<blocks, 256, 0, stream>>>(dst, deg_cursor, E);
    }
    scan_kernel<<<1, 1024, 0, stream>>>(deg_cursor, row_start, N);
    {
        int blocks = (int)((E + 255) / 256);
        scatter_csr_kernel<<<blocks, 256, 0, stream>>>(src, dst, deg_cursor, csr_src, E);
        // after this, deg_cursor[n] == segment end for node n
    }
    {
        int blocks = (N + 3) / 4;
        agg1_kernel<<<blocks, 256, 0, stream>>>(x, csr_src, row_start, deg_cursor, xsum, N);
    }
    {
        int blocks = (N + 255) / 256;
        mlpA_kernel<<<blocks, 256, 0, stream>>>(xsum, w1a, b1a, w2a, b2a, h1, N);
    }
    {
        int blocks = (N + 3) / 4;
        agg2_mlpB_kernel<<<blocks, 256, 0, stream>>>(h1, csr_src, row_start, deg_cursor,
                                                     w1b, b1b, w2b, b2b, wsv, z1, z2, N);
    }
    {
        int blocks = (C + 255) / 256;
        score_kernel<<<blocks, 256, 0, stream>>>(cand, z1, z2, bs, (float*)d_out, C);
    }
}